// Round 7
// baseline (1644.004 us; speedup 1.0000x reference)
//
#include <hip/hip_runtime.h>

#define N_NODES 20000
#define D 128
#define E_EDGES 320000
#define G 100
#define L_LAYERS 6
#define IN_DIM 5
#define ZROW (IN_DIM + D)
#define CUTOFF_V 10.0f
#define LOG2F_ 0.69314718055994530942f

typedef __attribute__((ext_vector_type(8))) short bf16x8;
typedef __attribute__((ext_vector_type(4))) float f32x4;
typedef unsigned short ushort_t;
typedef unsigned int uint_t;

__device__ __forceinline__ float sspf(float x) {
    // softplus(x)-log2 via fast hw exp/log (log arg in (1,2], well conditioned)
    return fmaxf(x, 0.0f) + __logf(1.0f + __expf(-fabsf(x))) - LOG2F_;
}

__device__ __forceinline__ ushort_t f2bf(float f) {
    union { float f; uint_t u; } x; x.f = f;
    uint_t r = ((x.u >> 16) & 1u) + 0x7fffu;
    return (ushort_t)((x.u + r) >> 16);
}

__device__ __forceinline__ uint_t pack2(float a, float b) {
    return (uint_t)f2bf(a) | ((uint_t)f2bf(b) << 16);
}

__device__ __forceinline__ f32x4 mfma_bf16(bf16x8 a, bf16x8 b, f32x4 c) {
    return __builtin_amdgcn_mfma_f32_16x16x32_bf16(a, b, c, 0, 0, 0);
}

// ---------------------------------------------------------------------------
__global__ void embed_kernel(const float* __restrict__ z,
                             const float* __restrict__ ew,
                             const float* __restrict__ eb,
                             float* __restrict__ h) {
    int n = blockIdx.x;
    int d = threadIdx.x;
    const float* zr = z + (size_t)n * ZROW;
    float acc = eb[d] + zr[IN_DIM + d];
#pragma unroll
    for (int k = 0; k < IN_DIM; ++k) acc += zr[k] * ew[d * IN_DIM + k];
    h[(size_t)n * D + d] = acc;
}

// ---------------------------------------------------------------------------
// mlp_w1 [L][D][G] -> bf16 [L][D][128] zero-padded in k
__global__ void convw1_kernel(const float* __restrict__ w1, ushort_t* __restrict__ out) {
    int idx = blockIdx.x * 256 + threadIdx.x;
    int k = idx & 127;
    int nl = idx >> 7;
    out[idx] = (k < G) ? f2bf(w1[(size_t)nl * G + k]) : (ushort_t)0;
}

__global__ void castbf_kernel(const float* __restrict__ src, ushort_t* __restrict__ dst) {
    int i = blockIdx.x * 256 + threadIdx.x;
    dst[i] = f2bf(src[i]);
}

// ---------------------------------------------------------------------------
// CSR build (edge graph constant across layers)
__global__ void hist_kernel(const int* __restrict__ ei, int* __restrict__ deg) {
    int e = blockIdx.x * 256 + threadIdx.x;
    atomicAdd(&deg[ei[E_EDGES + e]], 1);
}

__global__ __launch_bounds__(1024) void scan_kernel(const int* __restrict__ deg,
                                                    int* __restrict__ row_start,
                                                    int* __restrict__ cursor) {
    __shared__ int wsum[16];
    int t = threadIdx.x;
    const int CH = (N_NODES + 1023) / 1024;
    int base = t * CH;
    int s = 0;
    for (int i = 0; i < CH; ++i) {
        int idx = base + i;
        if (idx < N_NODES) s += deg[idx];
    }
    int lane = t & 63, wid = t >> 6;
    int v = s;
    for (int o = 1; o < 64; o <<= 1) {
        int u = __shfl_up(v, o, 64);
        if (lane >= o) v += u;
    }
    if (lane == 63) wsum[wid] = v;
    __syncthreads();
    if (t == 0) {
        int acc = 0;
        for (int i = 0; i < 16; ++i) { int tmp = wsum[i]; wsum[i] = acc; acc += tmp; }
    }
    __syncthreads();
    int run = v - s + wsum[wid];
    for (int i = 0; i < CH; ++i) {
        int idx = base + i;
        if (idx < N_NODES) {
            row_start[idx] = run;
            cursor[idx] = run;
            run += deg[idx];
        }
    }
    if (t == 0) row_start[N_NODES] = E_EDGES;
}

__global__ void scatter_perm_kernel(const int* __restrict__ ei, const float* __restrict__ el,
                                    int* __restrict__ cursor,
                                    int* __restrict__ perm, int* __restrict__ src_p,
                                    float* __restrict__ cm_p) {
    int e = blockIdx.x * 256 + threadIdx.x;
    int d = ei[E_EDGES + e];
    int p = atomicAdd(&cursor[d], 1);
    perm[p] = e;
    src_p[p] = ei[e];
    cm_p[p] = (el[e] <= CUTOFF_V) ? 1.0f : 0.0f;
}

// ---------------------------------------------------------------------------
// One-time: gather edge_attr rows into CSR-permuted, bf16, k-padded-to-128
// layout. 32 lanes per row (25 active float4 chunks), fully coalesced writes.
__global__ void attr_perm_kernel(const float* __restrict__ edge_attr,
                                 const int* __restrict__ perm,
                                 ushort_t* __restrict__ attr_p) {
    int tid = blockIdx.x * 256 + threadIdx.x;
    int r = tid >> 5, ch = tid & 31;
    float4 v = make_float4(0.f, 0.f, 0.f, 0.f);
    if (ch < 25) {
        int pe = perm[r];
        v = *(const float4*)(edge_attr + (size_t)pe * G + ch * 4);
    }
    uint2 p; p.x = pack2(v.x, v.y); p.y = pack2(v.z, v.w);
    *(uint2*)(attr_p + (size_t)r * 128 + ch * 4) = p;
}

// ---------------------------------------------------------------------------
// Fused edge MLP, transposed MFMA orientation, 2-wave cooperative ct-split,
// FOUR 32-edge tiles per block with register-prefetched attr:
//   GEMM1: D1[m=ucol][n=edge] = W1 . attr^T   (wave w computes ucols [64w,+64))
//   GEMM2: D2[m=wcol][n=edge] = W2 . u^T      (u via shared LDS transpose)
// R6 ledger: each block's serial phase chain exposed full attr-HBM latency
// every tile (block residency ~20 us vs ~1 us busy). Pipelining: tile t+1's
// attr loads issue right after tile t's GEMM1, hiding ~900cy HBM latency
// under ep1+barrier+GEMM2. Weight-load economy per edge unchanged (R5
// lesson). Full unroll -> compiler renames the prefetch set (no runtime
// indexing). NO min-waves hint (caps below natural demand = spill, R2/R3).
#define ETILES 4
__global__ __launch_bounds__(128) void edge_mlp_kernel(
    const ushort_t* __restrict__ attr_p, const float* __restrict__ cm_p,
    const ushort_t* __restrict__ w1b, const float* __restrict__ b1,
    const ushort_t* __restrict__ w2b, const float* __restrict__ b2,
    ushort_t* __restrict__ wf) {
    __shared__ __align__(16) ushort_t sT[32][136];

    int t = threadIdx.x, lane = t & 63, wid = t >> 6;
    int c = lane & 15, quad = lane >> 4;
    int eb0 = blockIdx.x * (32 * ETILES);
    int mbase = wid * 64;   // this wave's output-column base

    const ushort_t* arow0 = attr_p + (size_t)(eb0 + c) * 128 + quad * 8;
    const ushort_t* arow1 = attr_p + (size_t)(eb0 + 16 + c) * 128 + quad * 8;

    // prologue: attr for tile 0
    bf16x8 ar0[4], ar1[4];
#pragma unroll
    for (int ks = 0; ks < 4; ++ks) {
        ar0[ks] = *(const bf16x8*)(arow0 + ks * 32);
        ar1[ks] = *(const bf16x8*)(arow1 + ks * 32);
    }

#pragma unroll
    for (int tile = 0; tile < ETILES; ++tile) {
        f32x4 acc[2][4];
#pragma unroll
        for (int st = 0; st < 2; ++st)
#pragma unroll
            for (int ct = 0; ct < 4; ++ct) acc[st][ct] = (f32x4){0.f, 0.f, 0.f, 0.f};

        // GEMM1 (A = this wave's W1 half, L2-hot; B = prefetched attr regs)
#pragma unroll
        for (int ks = 0; ks < 4; ++ks) {
            int koff = ks * 32 + quad * 8;
#pragma unroll
            for (int ct = 0; ct < 4; ++ct) {
                bf16x8 a = *(const bf16x8*)(w1b + (size_t)(mbase + ct * 16 + c) * 128 + koff);
                acc[0][ct] = mfma_bf16(a, ar0[ks], acc[0][ct]);
                acc[1][ct] = mfma_bf16(a, ar1[ks], acc[1][ct]);
            }
        }

        // prefetch next tile's attr (HBM latency hides under ep1+barrier+GEMM2)
        bf16x8 nx0[4], nx1[4];
        if (tile + 1 < ETILES) {
            size_t toff = (size_t)(tile + 1) * 32 * 128;
#pragma unroll
            for (int ks = 0; ks < 4; ++ks) {
                nx0[ks] = *(const bf16x8*)(arow0 + toff + ks * 32);
                nx1[ks] = *(const bf16x8*)(arow1 + toff + ks * 32);
            }
        }

        // epilogue1: u = ssp(acc + b1) -> sT cols [mbase, mbase+64)
#pragma unroll
        for (int st = 0; st < 2; ++st)
#pragma unroll
            for (int ct = 0; ct < 4; ++ct) {
                int col = mbase + ct * 16 + quad * 4;
                float4 bv = *(const float4*)(b1 + col);
                uint2 p;
                p.x = pack2(sspf(acc[st][ct][0] + bv.x), sspf(acc[st][ct][1] + bv.y));
                p.y = pack2(sspf(acc[st][ct][2] + bv.z), sspf(acc[st][ct][3] + bv.w));
                *(uint2*)(&sT[st * 16 + c][col]) = p;
            }

        __syncthreads();   // both waves' u halves complete before K-sweep

        // GEMM2 (B = full-K u rows from LDS; A = this wave's W2 half)
#pragma unroll
        for (int st = 0; st < 2; ++st)
#pragma unroll
            for (int ct = 0; ct < 4; ++ct) acc[st][ct] = (f32x4){0.f, 0.f, 0.f, 0.f};
#pragma unroll
        for (int ks = 0; ks < 4; ++ks) {
            int koff = ks * 32 + quad * 8;
            bf16x8 b0  = *(const bf16x8*)(&sT[c][koff]);
            bf16x8 b1v = *(const bf16x8*)(&sT[16 + c][koff]);
#pragma unroll
            for (int ct = 0; ct < 4; ++ct) {
                bf16x8 a = *(const bf16x8*)(w2b + (size_t)(mbase + ct * 16 + c) * 128 + koff);
                acc[0][ct] = mfma_bf16(a, b0, acc[0][ct]);
                acc[1][ct] = mfma_bf16(a, b1v, acc[1][ct]);
            }
        }
        // epilogue2: Wf = (acc + b2) * C -> direct 8B global stores
#pragma unroll
        for (int st = 0; st < 2; ++st) {
            int e = eb0 + tile * 32 + st * 16 + c;
            float cv = cm_p[e];
#pragma unroll
            for (int ct = 0; ct < 4; ++ct) {
                int col = mbase + ct * 16 + quad * 4;
                float4 bv = *(const float4*)(b2 + col);
                uint2 p;
                p.x = pack2((acc[st][ct][0] + bv.x) * cv, (acc[st][ct][1] + bv.y) * cv);
                p.y = pack2((acc[st][ct][2] + bv.z) * cv, (acc[st][ct][3] + bv.w) * cv);
                *(uint2*)(wf + (size_t)e * 128 + col) = p;
            }
        }

        if (tile + 1 < ETILES) {
            __syncthreads();   // sT consumed by both waves before next ep1 overwrites
#pragma unroll
            for (int ks = 0; ks < 4; ++ks) { ar0[ks] = nx0[ks]; ar1[ks] = nx1[ks]; }
        }
    }
}

// ---------------------------------------------------------------------------
// Generic node GEMM on MFMA, same 2-wave ct-split; 32 nodes per 128-thread
// block (grid 625). Staging is shared (both waves write/read sT) -> barriers
// around it. out[node][col] = (opt RES) (opt SSP)( W . in^T + bias )
// TWOK: K=256, second 128-chunk staged from in1 (concat for update layer).
template <bool HASB, bool SSP, bool RES, bool BF16OUT, bool TWOK>
__global__ __launch_bounds__(128) void node_mfma_kernel(
    const float* __restrict__ in0, const float* __restrict__ in1,
    const ushort_t* __restrict__ Wb, const float* __restrict__ bias,
    const float* __restrict__ resid, void* __restrict__ outp) {
    __shared__ __align__(16) ushort_t sT[32][136];
    const int WS = TWOK ? 256 : 128;
    int t = threadIdx.x, lane = t & 63, wid = t >> 6;
    int c = lane & 15, quad = lane >> 4;
    int n0 = blockIdx.x * 32;
    int mbase = wid * 64;

    f32x4 acc[2][4];
#pragma unroll
    for (int st = 0; st < 2; ++st)
#pragma unroll
        for (int ct = 0; ct < 4; ++ct) acc[st][ct] = (f32x4){0.f, 0.f, 0.f, 0.f};

    const float* src = in0;
#pragma unroll 1
    for (int ph = 0; ph < (TWOK ? 2 : 1); ++ph) {
        if (ph) __syncthreads();   // don't overwrite sT while other wave reads
        // stage 32 rows fp32 -> bf16 LDS (8 iters x 128 threads = 32r x 32ch)
#pragma unroll
        for (int i = 0; i < 8; ++i) {
            int idx = i * 128 + t;
            int r = idx >> 5, ch = idx & 31;
            int gr = n0 + r;
            float4 v = make_float4(0.f, 0.f, 0.f, 0.f);
            if (gr < N_NODES) v = *(const float4*)(src + (size_t)gr * 128 + ch * 4);
            uint2 p; p.x = pack2(v.x, v.y); p.y = pack2(v.z, v.w);
            *(uint2*)(&sT[r][ch * 4]) = p;
        }
        __syncthreads();
        int kb = ph * 128;
#pragma unroll
        for (int ks = 0; ks < 4; ++ks) {
            int koff = ks * 32 + quad * 8;
            bf16x8 b0  = *(const bf16x8*)(&sT[c][koff]);
            bf16x8 b1v = *(const bf16x8*)(&sT[16 + c][koff]);
#pragma unroll
            for (int ct = 0; ct < 4; ++ct) {
                bf16x8 a = *(const bf16x8*)(Wb + (size_t)(mbase + ct * 16 + c) * WS + kb + koff);
                acc[0][ct] = mfma_bf16(a, b0, acc[0][ct]);
                acc[1][ct] = mfma_bf16(a, b1v, acc[1][ct]);
            }
        }
        src = in1;
    }

#pragma unroll
    for (int st = 0; st < 2; ++st) {
        int node = n0 + st * 16 + c;
        if (node < N_NODES) {
#pragma unroll
            for (int ct = 0; ct < 4; ++ct) {
                int col = mbase + ct * 16 + quad * 4;
                float4 bv = make_float4(0.f, 0.f, 0.f, 0.f);
                if (HASB) bv = *(const float4*)(bias + col);
                float v0 = acc[st][ct][0] + bv.x;
                float v1 = acc[st][ct][1] + bv.y;
                float v2 = acc[st][ct][2] + bv.z;
                float v3 = acc[st][ct][3] + bv.w;
                if (SSP) { v0 = sspf(v0); v1 = sspf(v1); v2 = sspf(v2); v3 = sspf(v3); }
                if (RES) {
                    float4 rv = *(const float4*)(resid + (size_t)node * 128 + col);
                    v0 += rv.x; v1 += rv.y; v2 += rv.z; v3 += rv.w;
                }
                if (BF16OUT) {
                    uint2 p; p.x = pack2(v0, v1); p.y = pack2(v2, v3);
                    *(uint2*)((ushort_t*)outp + (size_t)node * 128 + col) = p;
                } else {
                    *(float4*)((float*)outp + (size_t)node * 128 + col) =
                        make_float4(v0, v1, v2, v3);
                }
            }
        }
    }
}

// ---------------------------------------------------------------------------
// Segment sum: one wave per dst node, 2 cols/lane; wf and xf both bf16.
__global__ __launch_bounds__(256) void segsum_kernel(
    const ushort_t* __restrict__ wf, const ushort_t* __restrict__ xf_bf,
    const int* __restrict__ row_start, const int* __restrict__ src_p,
    float* __restrict__ m_i) {
    int t = threadIdx.x, lane = t & 63;
    int n = blockIdx.x * 4 + (t >> 6);
    int beg = row_start[n], end = row_start[n + 1];
    float a0 = 0.f, a1 = 0.f;
    for (int i = beg; i < end; ++i) {
        uint_t w = *(const uint_t*)(wf + (size_t)i * 128 + lane * 2);
        uint_t x = *(const uint_t*)(xf_bf + (size_t)src_p[i] * 128 + lane * 2);
        a0 += __uint_as_float(w << 16) * __uint_as_float(x << 16);
        a1 += __uint_as_float(w & 0xffff0000u) * __uint_as_float(x & 0xffff0000u);
    }
    *(float2*)(m_i + (size_t)n * 128 + lane * 2) = make_float2(a0, a1);
}

// ---------------------------------------------------------------------------
extern "C" void kernel_launch(void* const* d_in, const int* in_sizes, int n_in,
                              void* d_out, int out_size, void* d_ws, size_t ws_size,
                              hipStream_t stream) {
    const float* z        = (const float*)d_in[0];
    const int*   ei       = (const int*)d_in[1];
    const float* el       = (const float*)d_in[2];
    const float* ea       = (const float*)d_in[3];
    const float* emblin_w = (const float*)d_in[4];
    const float* emblin_b = (const float*)d_in[5];
    const float* mlp_w1   = (const float*)d_in[6];
    const float* mlp_b1   = (const float*)d_in[7];
    const float* mlp_w2   = (const float*)d_in[8];
    const float* mlp_b2   = (const float*)d_in[9];
    const float* lin1_w   = (const float*)d_in[10];
    const float* lin2_w   = (const float*)d_in[11];
    const float* lin2_b   = (const float*)d_in[12];
    const float* lin_w    = (const float*)d_in[13];
    const float* lin_b    = (const float*)d_in[14];
    (void)in_sizes; (void)n_in; (void)out_size; (void)ws_size;

    const size_t ND = (size_t)N_NODES * D;
    float* ws   = (float*)d_ws;
    float* h    = ws;                // N*D fp32
    float* m_i  = h + ND;            // N*D fp32
    float* cm_p = m_i + ND;          // E fp32 (cutoff mask, CSR-permuted)
    float* fend = cm_p + E_EDGES;

    ushort_t* w1b    = (ushort_t*)fend;                     // L*D*128
    ushort_t* w2b    = w1b   + (size_t)L_LAYERS * D * 128;  // L*D*D
    ushort_t* lin1b  = w2b   + (size_t)L_LAYERS * D * D;    // L*D*D
    ushort_t* lin2b  = lin1b + (size_t)L_LAYERS * D * D;    // L*D*D
    ushort_t* linwb  = lin2b + (size_t)L_LAYERS * D * D;    // L*D*256
    ushort_t* wf     = linwb + (size_t)L_LAYERS * D * 256;  // E*128
    ushort_t* xf_bf  = wf    + (size_t)E_EDGES * 128;       // N*128
    ushort_t* attr_p = xf_bf + ND;                          // E*128 (bf16, permuted, k-padded)
    int* ibase      = (int*)(attr_p + (size_t)E_EDGES * 128);
    int* deg        = ibase;                 // N
    int* row_start  = deg + N_NODES;         // N+1
    int* cursor     = row_start + N_NODES + 1;
    int* perm       = cursor + N_NODES;      // E
    int* src_p      = perm + E_EDGES;        // E

    // one-time weight prep (all bf16, row-major [out][k] = A-fragment layout)
    convw1_kernel<<<(L_LAYERS * D * 128) / 256, 256, 0, stream>>>(mlp_w1, w1b);
    castbf_kernel<<<(L_LAYERS * D * D) / 256, 256, 0, stream>>>(mlp_w2, w2b);
    castbf_kernel<<<(L_LAYERS * D * D) / 256, 256, 0, stream>>>(lin1_w, lin1b);
    castbf_kernel<<<(L_LAYERS * D * D) / 256, 256, 0, stream>>>(lin2_w, lin2b);
    castbf_kernel<<<(L_LAYERS * D * 256) / 256, 256, 0, stream>>>(lin_w, linwb);

    // CSR build
    hipMemsetAsync(deg, 0, (size_t)N_NODES * sizeof(int), stream);
    hist_kernel<<<E_EDGES / 256, 256, 0, stream>>>(ei, deg);
    scan_kernel<<<1, 1024, 0, stream>>>(deg, row_start, cursor);
    scatter_perm_kernel<<<E_EDGES / 256, 256, 0, stream>>>(ei, el, cursor, perm, src_p, cm_p);
    // one-time attr gather->bf16->permuted (hoisted out of the layer loop)
    attr_perm_kernel<<<(E_EDGES * 32) / 256, 256, 0, stream>>>(ea, perm, attr_p);

    embed_kernel<<<N_NODES, D, 0, stream>>>(z, emblin_w, emblin_b, h);

    const int NBLK = (N_NODES + 31) / 32;   // 625, two waves per block
    for (int l = 0; l < L_LAYERS; ++l) {
        // xf_bf = h @ lin1^T   (bf16 out, no bias)
        node_mfma_kernel<false, false, false, true, false><<<NBLK, 128, 0, stream>>>(
            h, nullptr, lin1b + (size_t)l * D * D, nullptr, nullptr, xf_bf);
        edge_mlp_kernel<<<E_EDGES / (32 * ETILES), 128, 0, stream>>>(
            attr_p, cm_p, w1b + (size_t)l * D * 128, mlp_b1 + (size_t)l * D,
            w2b + (size_t)l * D * D, mlp_b2 + (size_t)l * D, wf);
        segsum_kernel<<<N_NODES / 4, 256, 0, stream>>>(wf, xf_bf, row_start, src_p, m_i);
        // m_i = ssp(m_i @ lin2^T + b)   (in place, fp32)
        node_mfma_kernel<true, true, false, false, false><<<NBLK, 128, 0, stream>>>(
            m_i, nullptr, lin2b + (size_t)l * D * D, lin2_b + (size_t)l * D,
            nullptr, m_i);
        // h = h + concat(h, m_i) @ lin_w^T + b   (in place)
        node_mfma_kernel<true, false, true, false, true><<<NBLK, 128, 0, stream>>>(
            h, m_i, linwb + (size_t)l * D * 256, lin_b + (size_t)l * D, h, h);
    }

    hipMemcpyAsync(d_out, h, ND * sizeof(float), hipMemcpyDeviceToDevice, stream);
}

// Round 8
// 1522.495 us; speedup vs baseline: 1.0798x; 1.0798x over previous
//
#include <hip/hip_runtime.h>

#define N_NODES 20000
#define D 128
#define E_EDGES 320000
#define G 100
#define L_LAYERS 6
#define IN_DIM 5
#define ZROW (IN_DIM + D)
#define CUTOFF_V 10.0f
#define LOG2F_ 0.69314718055994530942f

typedef __attribute__((ext_vector_type(8))) short bf16x8;
typedef __attribute__((ext_vector_type(4))) float f32x4;
typedef unsigned short ushort_t;
typedef unsigned int uint_t;

__device__ __forceinline__ float sspf(float x) {
    // softplus(x)-log2 via fast hw exp/log (log arg in (1,2], well conditioned)
    return fmaxf(x, 0.0f) + __logf(1.0f + __expf(-fabsf(x))) - LOG2F_;
}

__device__ __forceinline__ ushort_t f2bf(float f) {
    union { float f; uint_t u; } x; x.f = f;
    uint_t r = ((x.u >> 16) & 1u) + 0x7fffu;
    return (ushort_t)((x.u + r) >> 16);
}

__device__ __forceinline__ uint_t pack2(float a, float b) {
    return (uint_t)f2bf(a) | ((uint_t)f2bf(b) << 16);
}

__device__ __forceinline__ f32x4 mfma_bf16(bf16x8 a, bf16x8 b, f32x4 c) {
    return __builtin_amdgcn_mfma_f32_16x16x32_bf16(a, b, c, 0, 0, 0);
}

// ---------------------------------------------------------------------------
__global__ void embed_kernel(const float* __restrict__ z,
                             const float* __restrict__ ew,
                             const float* __restrict__ eb,
                             float* __restrict__ h) {
    int n = blockIdx.x;
    int d = threadIdx.x;
    const float* zr = z + (size_t)n * ZROW;
    float acc = eb[d] + zr[IN_DIM + d];
#pragma unroll
    for (int k = 0; k < IN_DIM; ++k) acc += zr[k] * ew[d * IN_DIM + k];
    h[(size_t)n * D + d] = acc;
}

// ---------------------------------------------------------------------------
// mlp_w1 [L][D][G] -> bf16 [L][D][128] zero-padded in k
__global__ void convw1_kernel(const float* __restrict__ w1, ushort_t* __restrict__ out) {
    int idx = blockIdx.x * 256 + threadIdx.x;
    int k = idx & 127;
    int nl = idx >> 7;
    out[idx] = (k < G) ? f2bf(w1[(size_t)nl * G + k]) : (ushort_t)0;
}

__global__ void castbf_kernel(const float* __restrict__ src, ushort_t* __restrict__ dst) {
    int i = blockIdx.x * 256 + threadIdx.x;
    dst[i] = f2bf(src[i]);
}

// ---------------------------------------------------------------------------
// CSR build (edge graph constant across layers)
__global__ void hist_kernel(const int* __restrict__ ei, int* __restrict__ deg) {
    int e = blockIdx.x * 256 + threadIdx.x;
    atomicAdd(&deg[ei[E_EDGES + e]], 1);
}

__global__ __launch_bounds__(1024) void scan_kernel(const int* __restrict__ deg,
                                                    int* __restrict__ row_start,
                                                    int* __restrict__ cursor) {
    __shared__ int wsum[16];
    int t = threadIdx.x;
    const int CH = (N_NODES + 1023) / 1024;
    int base = t * CH;
    int s = 0;
    for (int i = 0; i < CH; ++i) {
        int idx = base + i;
        if (idx < N_NODES) s += deg[idx];
    }
    int lane = t & 63, wid = t >> 6;
    int v = s;
    for (int o = 1; o < 64; o <<= 1) {
        int u = __shfl_up(v, o, 64);
        if (lane >= o) v += u;
    }
    if (lane == 63) wsum[wid] = v;
    __syncthreads();
    if (t == 0) {
        int acc = 0;
        for (int i = 0; i < 16; ++i) { int tmp = wsum[i]; wsum[i] = acc; acc += tmp; }
    }
    __syncthreads();
    int run = v - s + wsum[wid];
    for (int i = 0; i < CH; ++i) {
        int idx = base + i;
        if (idx < N_NODES) {
            row_start[idx] = run;
            cursor[idx] = run;
            run += deg[idx];
        }
    }
    if (t == 0) row_start[N_NODES] = E_EDGES;
}

__global__ void scatter_perm_kernel(const int* __restrict__ ei, const float* __restrict__ el,
                                    int* __restrict__ cursor,
                                    int* __restrict__ perm, int* __restrict__ src_p,
                                    float* __restrict__ cm_p) {
    int e = blockIdx.x * 256 + threadIdx.x;
    int d = ei[E_EDGES + e];
    int p = atomicAdd(&cursor[d], 1);
    perm[p] = e;
    src_p[p] = ei[e];
    cm_p[p] = (el[e] <= CUTOFF_V) ? 1.0f : 0.0f;
}

// ---------------------------------------------------------------------------
// One-time: gather edge_attr rows into CSR-permuted, bf16, k-padded-to-128
// layout. 32 lanes per row (25 active float4 chunks), fully coalesced writes.
__global__ void attr_perm_kernel(const float* __restrict__ edge_attr,
                                 const int* __restrict__ perm,
                                 ushort_t* __restrict__ attr_p) {
    int tid = blockIdx.x * 256 + threadIdx.x;
    int r = tid >> 5, ch = tid & 31;
    float4 v = make_float4(0.f, 0.f, 0.f, 0.f);
    if (ch < 25) {
        int pe = perm[r];
        v = *(const float4*)(edge_attr + (size_t)pe * G + ch * 4);
    }
    uint2 p; p.x = pack2(v.x, v.y); p.y = pack2(v.z, v.w);
    *(uint2*)(attr_p + (size_t)r * 128 + ch * 4) = p;
}

// ---------------------------------------------------------------------------
// Fused edge MLP, transposed MFMA orientation, FOUR-wave cooperative
// ct-split (each wave owns 32 of 128 output cols):
//   GEMM1: D1[m=ucol][n=edge] = W1 . attr^T
//   GEMM2: D2[m=wcol][n=edge] = W2 . u^T   (u via shared LDS transpose)
// 32 edges per 256-thread block. Ledger R4/R6/R7: resident-wave count is the
// dominant lever; any per-wave register spend that cuts occupancy loses
// (R7: +44 VGPR prefetch -> occ 40->17.5%, dur +24%). 4-way split cuts acc
// to 16 regs and per-wave weight loads to a disjoint QUARTER of W1/W2
// (per-block weight economy unchanged, R5 lesson). attr B-frags read by all
// 4 waves (L2-hit duplicates, no HBM delta). NO min-waves hint (R2/R3:
// caps below natural demand = scratch spill).
__global__ __launch_bounds__(256) void edge_mlp_kernel(
    const ushort_t* __restrict__ attr_p, const float* __restrict__ cm_p,
    const ushort_t* __restrict__ w1b, const float* __restrict__ b1,
    const ushort_t* __restrict__ w2b, const float* __restrict__ b2,
    ushort_t* __restrict__ wf) {
    __shared__ __align__(16) ushort_t sT[32][136];

    int t = threadIdx.x, lane = t & 63, wid = t >> 6;   // wid 0..3
    int c = lane & 15, quad = lane >> 4;
    int er0 = blockIdx.x * 32;
    int mbase = wid * 32;   // this wave's output-column base

    f32x4 acc[2][2];
#pragma unroll
    for (int st = 0; st < 2; ++st)
#pragma unroll
        for (int ct = 0; ct < 2; ++ct) acc[st][ct] = (f32x4){0.f, 0.f, 0.f, 0.f};

    // GEMM1 (A = this wave's W1 quarter, L2-hot; B = attr_p strips)
#pragma unroll
    for (int ks = 0; ks < 4; ++ks) {
        int koff = ks * 32 + quad * 8;
        bf16x8 b0  = *(const bf16x8*)(attr_p + (size_t)(er0 + c) * 128 + koff);
        bf16x8 b1v = *(const bf16x8*)(attr_p + (size_t)(er0 + 16 + c) * 128 + koff);
#pragma unroll
        for (int ct = 0; ct < 2; ++ct) {
            bf16x8 a = *(const bf16x8*)(w1b + (size_t)(mbase + ct * 16 + c) * 128 + koff);
            acc[0][ct] = mfma_bf16(a, b0, acc[0][ct]);
            acc[1][ct] = mfma_bf16(a, b1v, acc[1][ct]);
        }
    }
    // epilogue1: u = ssp(acc + b1) -> sT cols [mbase, mbase+32)
#pragma unroll
    for (int st = 0; st < 2; ++st)
#pragma unroll
        for (int ct = 0; ct < 2; ++ct) {
            int col = mbase + ct * 16 + quad * 4;
            float4 bv = *(const float4*)(b1 + col);
            uint2 p;
            p.x = pack2(sspf(acc[st][ct][0] + bv.x), sspf(acc[st][ct][1] + bv.y));
            p.y = pack2(sspf(acc[st][ct][2] + bv.z), sspf(acc[st][ct][3] + bv.w));
            *(uint2*)(&sT[st * 16 + c][col]) = p;
        }

    __syncthreads();   // all four u quarters complete before K-sweep

    // GEMM2 (B = full-K u rows from LDS; A = this wave's W2 quarter)
#pragma unroll
    for (int st = 0; st < 2; ++st)
#pragma unroll
        for (int ct = 0; ct < 2; ++ct) acc[st][ct] = (f32x4){0.f, 0.f, 0.f, 0.f};
#pragma unroll
    for (int ks = 0; ks < 4; ++ks) {
        int koff = ks * 32 + quad * 8;
        bf16x8 b0  = *(const bf16x8*)(&sT[c][koff]);
        bf16x8 b1v = *(const bf16x8*)(&sT[16 + c][koff]);
#pragma unroll
        for (int ct = 0; ct < 2; ++ct) {
            bf16x8 a = *(const bf16x8*)(w2b + (size_t)(mbase + ct * 16 + c) * 128 + koff);
            acc[0][ct] = mfma_bf16(a, b0, acc[0][ct]);
            acc[1][ct] = mfma_bf16(a, b1v, acc[1][ct]);
        }
    }
    // epilogue2: Wf = (acc + b2) * C -> direct 8B global stores
#pragma unroll
    for (int st = 0; st < 2; ++st) {
        int e = er0 + st * 16 + c;
        float cv = cm_p[e];
#pragma unroll
        for (int ct = 0; ct < 2; ++ct) {
            int col = mbase + ct * 16 + quad * 4;
            float4 bv = *(const float4*)(b2 + col);
            uint2 p;
            p.x = pack2((acc[st][ct][0] + bv.x) * cv, (acc[st][ct][1] + bv.y) * cv);
            p.y = pack2((acc[st][ct][2] + bv.z) * cv, (acc[st][ct][3] + bv.w) * cv);
            *(uint2*)(wf + (size_t)e * 128 + col) = p;
        }
    }
}

// ---------------------------------------------------------------------------
// Generic node GEMM on MFMA, same FOUR-wave ct-split; 32 nodes per
// 256-thread block (grid 625). Staging shared by all waves -> barriers
// around it. out[node][col] = (opt RES) (opt SSP)( W . in^T + bias )
// TWOK: K=256, second 128-chunk staged from in1 (concat for update layer).
template <bool HASB, bool SSP, bool RES, bool BF16OUT, bool TWOK>
__global__ __launch_bounds__(256) void node_mfma_kernel(
    const float* __restrict__ in0, const float* __restrict__ in1,
    const ushort_t* __restrict__ Wb, const float* __restrict__ bias,
    const float* __restrict__ resid, void* __restrict__ outp) {
    __shared__ __align__(16) ushort_t sT[32][136];
    const int WS = TWOK ? 256 : 128;
    int t = threadIdx.x, lane = t & 63, wid = t >> 6;   // wid 0..3
    int c = lane & 15, quad = lane >> 4;
    int n0 = blockIdx.x * 32;
    int mbase = wid * 32;

    f32x4 acc[2][2];
#pragma unroll
    for (int st = 0; st < 2; ++st)
#pragma unroll
        for (int ct = 0; ct < 2; ++ct) acc[st][ct] = (f32x4){0.f, 0.f, 0.f, 0.f};

    const float* src = in0;
#pragma unroll 1
    for (int ph = 0; ph < (TWOK ? 2 : 1); ++ph) {
        if (ph) __syncthreads();   // don't overwrite sT while other waves read
        // stage 32 rows fp32 -> bf16 LDS (4 iters x 256 threads = 32r x 32ch)
#pragma unroll
        for (int i = 0; i < 4; ++i) {
            int idx = i * 256 + t;
            int r = idx >> 5, ch = idx & 31;
            int gr = n0 + r;
            float4 v = make_float4(0.f, 0.f, 0.f, 0.f);
            if (gr < N_NODES) v = *(const float4*)(src + (size_t)gr * 128 + ch * 4);
            uint2 p; p.x = pack2(v.x, v.y); p.y = pack2(v.z, v.w);
            *(uint2*)(&sT[r][ch * 4]) = p;
        }
        __syncthreads();
        int kb = ph * 128;
#pragma unroll
        for (int ks = 0; ks < 4; ++ks) {
            int koff = ks * 32 + quad * 8;
            bf16x8 b0  = *(const bf16x8*)(&sT[c][koff]);
            bf16x8 b1v = *(const bf16x8*)(&sT[16 + c][koff]);
#pragma unroll
            for (int ct = 0; ct < 2; ++ct) {
                bf16x8 a = *(const bf16x8*)(Wb + (size_t)(mbase + ct * 16 + c) * WS + kb + koff);
                acc[0][ct] = mfma_bf16(a, b0, acc[0][ct]);
                acc[1][ct] = mfma_bf16(a, b1v, acc[1][ct]);
            }
        }
        src = in1;
    }

#pragma unroll
    for (int st = 0; st < 2; ++st) {
        int node = n0 + st * 16 + c;
        if (node < N_NODES) {
#pragma unroll
            for (int ct = 0; ct < 2; ++ct) {
                int col = mbase + ct * 16 + quad * 4;
                float4 bv = make_float4(0.f, 0.f, 0.f, 0.f);
                if (HASB) bv = *(const float4*)(bias + col);
                float v0 = acc[st][ct][0] + bv.x;
                float v1 = acc[st][ct][1] + bv.y;
                float v2 = acc[st][ct][2] + bv.z;
                float v3 = acc[st][ct][3] + bv.w;
                if (SSP) { v0 = sspf(v0); v1 = sspf(v1); v2 = sspf(v2); v3 = sspf(v3); }
                if (RES) {
                    float4 rv = *(const float4*)(resid + (size_t)node * 128 + col);
                    v0 += rv.x; v1 += rv.y; v2 += rv.z; v3 += rv.w;
                }
                if (BF16OUT) {
                    uint2 p; p.x = pack2(v0, v1); p.y = pack2(v2, v3);
                    *(uint2*)((ushort_t*)outp + (size_t)node * 128 + col) = p;
                } else {
                    *(float4*)((float*)outp + (size_t)node * 128 + col) =
                        make_float4(v0, v1, v2, v3);
                }
            }
        }
    }
}

// ---------------------------------------------------------------------------
// Segment sum: one wave per dst node, 2 cols/lane; wf and xf both bf16.
__global__ __launch_bounds__(256) void segsum_kernel(
    const ushort_t* __restrict__ wf, const ushort_t* __restrict__ xf_bf,
    const int* __restrict__ row_start, const int* __restrict__ src_p,
    float* __restrict__ m_i) {
    int t = threadIdx.x, lane = t & 63;
    int n = blockIdx.x * 4 + (t >> 6);
    int beg = row_start[n], end = row_start[n + 1];
    float a0 = 0.f, a1 = 0.f;
    for (int i = beg; i < end; ++i) {
        uint_t w = *(const uint_t*)(wf + (size_t)i * 128 + lane * 2);
        uint_t x = *(const uint_t*)(xf_bf + (size_t)src_p[i] * 128 + lane * 2);
        a0 += __uint_as_float(w << 16) * __uint_as_float(x << 16);
        a1 += __uint_as_float(w & 0xffff0000u) * __uint_as_float(x & 0xffff0000u);
    }
    *(float2*)(m_i + (size_t)n * 128 + lane * 2) = make_float2(a0, a1);
}

// ---------------------------------------------------------------------------
extern "C" void kernel_launch(void* const* d_in, const int* in_sizes, int n_in,
                              void* d_out, int out_size, void* d_ws, size_t ws_size,
                              hipStream_t stream) {
    const float* z        = (const float*)d_in[0];
    const int*   ei       = (const int*)d_in[1];
    const float* el       = (const float*)d_in[2];
    const float* ea       = (const float*)d_in[3];
    const float* emblin_w = (const float*)d_in[4];
    const float* emblin_b = (const float*)d_in[5];
    const float* mlp_w1   = (const float*)d_in[6];
    const float* mlp_b1   = (const float*)d_in[7];
    const float* mlp_w2   = (const float*)d_in[8];
    const float* mlp_b2   = (const float*)d_in[9];
    const float* lin1_w   = (const float*)d_in[10];
    const float* lin2_w   = (const float*)d_in[11];
    const float* lin2_b   = (const float*)d_in[12];
    const float* lin_w    = (const float*)d_in[13];
    const float* lin_b    = (const float*)d_in[14];
    (void)in_sizes; (void)n_in; (void)out_size; (void)ws_size;

    const size_t ND = (size_t)N_NODES * D;
    float* ws   = (float*)d_ws;
    float* h    = ws;                // N*D fp32
    float* m_i  = h + ND;            // N*D fp32
    float* cm_p = m_i + ND;          // E fp32 (cutoff mask, CSR-permuted)
    float* fend = cm_p + E_EDGES;

    ushort_t* w1b    = (ushort_t*)fend;                     // L*D*128
    ushort_t* w2b    = w1b   + (size_t)L_LAYERS * D * 128;  // L*D*D
    ushort_t* lin1b  = w2b   + (size_t)L_LAYERS * D * D;    // L*D*D
    ushort_t* lin2b  = lin1b + (size_t)L_LAYERS * D * D;    // L*D*D
    ushort_t* linwb  = lin2b + (size_t)L_LAYERS * D * D;    // L*D*256
    ushort_t* wf     = linwb + (size_t)L_LAYERS * D * 256;  // E*128
    ushort_t* xf_bf  = wf    + (size_t)E_EDGES * 128;       // N*128
    ushort_t* attr_p = xf_bf + ND;                          // E*128 (bf16, permuted, k-padded)
    int* ibase      = (int*)(attr_p + (size_t)E_EDGES * 128);
    int* deg        = ibase;                 // N
    int* row_start  = deg + N_NODES;         // N+1
    int* cursor     = row_start + N_NODES + 1;
    int* perm       = cursor + N_NODES;      // E
    int* src_p      = perm + E_EDGES;        // E

    // one-time weight prep (all bf16, row-major [out][k] = A-fragment layout)
    convw1_kernel<<<(L_LAYERS * D * 128) / 256, 256, 0, stream>>>(mlp_w1, w1b);
    castbf_kernel<<<(L_LAYERS * D * D) / 256, 256, 0, stream>>>(mlp_w2, w2b);
    castbf_kernel<<<(L_LAYERS * D * D) / 256, 256, 0, stream>>>(lin1_w, lin1b);
    castbf_kernel<<<(L_LAYERS * D * D) / 256, 256, 0, stream>>>(lin2_w, lin2b);
    castbf_kernel<<<(L_LAYERS * D * 256) / 256, 256, 0, stream>>>(lin_w, linwb);

    // CSR build
    hipMemsetAsync(deg, 0, (size_t)N_NODES * sizeof(int), stream);
    hist_kernel<<<E_EDGES / 256, 256, 0, stream>>>(ei, deg);
    scan_kernel<<<1, 1024, 0, stream>>>(deg, row_start, cursor);
    scatter_perm_kernel<<<E_EDGES / 256, 256, 0, stream>>>(ei, el, cursor, perm, src_p, cm_p);
    // one-time attr gather->bf16->permuted (hoisted out of the layer loop)
    attr_perm_kernel<<<(E_EDGES * 32) / 256, 256, 0, stream>>>(ea, perm, attr_p);

    embed_kernel<<<N_NODES, D, 0, stream>>>(z, emblin_w, emblin_b, h);

    const int NBLK = (N_NODES + 31) / 32;   // 625, four waves per block
    for (int l = 0; l < L_LAYERS; ++l) {
        // xf_bf = h @ lin1^T   (bf16 out, no bias)
        node_mfma_kernel<false, false, false, true, false><<<NBLK, 256, 0, stream>>>(
            h, nullptr, lin1b + (size_t)l * D * D, nullptr, nullptr, xf_bf);
        edge_mlp_kernel<<<E_EDGES / 32, 256, 0, stream>>>(
            attr_p, cm_p, w1b + (size_t)l * D * 128, mlp_b1 + (size_t)l * D,
            w2b + (size_t)l * D * D, mlp_b2 + (size_t)l * D, wf);
        segsum_kernel<<<N_NODES / 4, 256, 0, stream>>>(wf, xf_bf, row_start, src_p, m_i);
        // m_i = ssp(m_i @ lin2^T + b)   (in place, fp32)
        node_mfma_kernel<true, true, false, false, false><<<NBLK, 256, 0, stream>>>(
            m_i, nullptr, lin2b + (size_t)l * D * D, lin2_b + (size_t)l * D,
            nullptr, m_i);
        // h = h + concat(h, m_i) @ lin_w^T + b   (in place)
        node_mfma_kernel<true, false, true, false, true><<<NBLK, 256, 0, stream>>>(
            h, m_i, linwb + (size_t)l * D * 256, lin_b + (size_t)l * D, h, h);
    }

    hipMemcpyAsync(d_out, h, ND * sizeof(float), hipMemcpyDeviceToDevice, stream);
}

// Round 10
// 1400.682 us; speedup vs baseline: 1.1737x; 1.0870x over previous
//
#include <hip/hip_runtime.h>

#define N_NODES 20000
#define D 128
#define E_EDGES 320000
#define G 100
#define L_LAYERS 6
#define IN_DIM 5
#define ZROW (IN_DIM + D)
#define CUTOFF_V 10.0f
#define LOG2F_ 0.69314718055994530942f

typedef __attribute__((ext_vector_type(8))) short bf16x8;
typedef __attribute__((ext_vector_type(4))) float f32x4;
typedef unsigned short ushort_t;
typedef unsigned int uint_t;

__device__ __forceinline__ float sspf(float x) {
    // softplus(x)-log2 via fast hw exp/log (log arg in (1,2], well conditioned)
    return fmaxf(x, 0.0f) + __logf(1.0f + __expf(-fabsf(x))) - LOG2F_;
}

__device__ __forceinline__ ushort_t f2bf(float f) {
    union { float f; uint_t u; } x; x.f = f;
    uint_t r = ((x.u >> 16) & 1u) + 0x7fffu;
    return (ushort_t)((x.u + r) >> 16);
}

__device__ __forceinline__ uint_t pack2(float a, float b) {
    return (uint_t)f2bf(a) | ((uint_t)f2bf(b) << 16);
}

__device__ __forceinline__ f32x4 mfma_bf16(bf16x8 a, bf16x8 b, f32x4 c) {
    return __builtin_amdgcn_mfma_f32_16x16x32_bf16(a, b, c, 0, 0, 0);
}

// ---------------------------------------------------------------------------
__global__ void embed_kernel(const float* __restrict__ z,
                             const float* __restrict__ ew,
                             const float* __restrict__ eb,
                             float* __restrict__ h) {
    int n = blockIdx.x;
    int d = threadIdx.x;
    const float* zr = z + (size_t)n * ZROW;
    float acc = eb[d] + zr[IN_DIM + d];
#pragma unroll
    for (int k = 0; k < IN_DIM; ++k) acc += zr[k] * ew[d * IN_DIM + k];
    h[(size_t)n * D + d] = acc;
}

// ---------------------------------------------------------------------------
// mlp_w1 [L][D][G] -> bf16 [L][D][128] zero-padded in k
__global__ void convw1_kernel(const float* __restrict__ w1, ushort_t* __restrict__ out) {
    int idx = blockIdx.x * 256 + threadIdx.x;
    int k = idx & 127;
    int nl = idx >> 7;
    out[idx] = (k < G) ? f2bf(w1[(size_t)nl * G + k]) : (ushort_t)0;
}

__global__ void castbf_kernel(const float* __restrict__ src, ushort_t* __restrict__ dst) {
    int i = blockIdx.x * 256 + threadIdx.x;
    dst[i] = f2bf(src[i]);
}

// ---------------------------------------------------------------------------
// CSR build (edge graph constant across layers)
__global__ void hist_kernel(const int* __restrict__ ei, int* __restrict__ deg) {
    int e = blockIdx.x * 256 + threadIdx.x;
    atomicAdd(&deg[ei[E_EDGES + e]], 1);
}

__global__ __launch_bounds__(1024) void scan_kernel(const int* __restrict__ deg,
                                                    int* __restrict__ row_start,
                                                    int* __restrict__ cursor) {
    __shared__ int wsum[16];
    int t = threadIdx.x;
    const int CH = (N_NODES + 1023) / 1024;
    int base = t * CH;
    int s = 0;
    for (int i = 0; i < CH; ++i) {
        int idx = base + i;
        if (idx < N_NODES) s += deg[idx];
    }
    int lane = t & 63, wid = t >> 6;
    int v = s;
    for (int o = 1; o < 64; o <<= 1) {
        int u = __shfl_up(v, o, 64);
        if (lane >= o) v += u;
    }
    if (lane == 63) wsum[wid] = v;
    __syncthreads();
    if (t == 0) {
        int acc = 0;
        for (int i = 0; i < 16; ++i) { int tmp = wsum[i]; wsum[i] = acc; acc += tmp; }
    }
    __syncthreads();
    int run = v - s + wsum[wid];
    for (int i = 0; i < CH; ++i) {
        int idx = base + i;
        if (idx < N_NODES) {
            row_start[idx] = run;
            cursor[idx] = run;
            run += deg[idx];
        }
    }
    if (t == 0) row_start[N_NODES] = E_EDGES;
}

__global__ void scatter_perm_kernel(const int* __restrict__ ei, const float* __restrict__ el,
                                    int* __restrict__ cursor,
                                    int* __restrict__ perm, int* __restrict__ src_p,
                                    float* __restrict__ cm_p) {
    int e = blockIdx.x * 256 + threadIdx.x;
    int d = ei[E_EDGES + e];
    int p = atomicAdd(&cursor[d], 1);
    perm[p] = e;
    src_p[p] = ei[e];
    cm_p[p] = (el[e] <= CUTOFF_V) ? 1.0f : 0.0f;
}

// ---------------------------------------------------------------------------
// One-time: gather edge_attr rows into CSR-permuted, bf16, k-padded-to-128
// layout. 32 lanes per row (25 active float4 chunks), fully coalesced writes.
__global__ void attr_perm_kernel(const float* __restrict__ edge_attr,
                                 const int* __restrict__ perm,
                                 ushort_t* __restrict__ attr_p) {
    int tid = blockIdx.x * 256 + threadIdx.x;
    int r = tid >> 5, ch = tid & 31;
    float4 v = make_float4(0.f, 0.f, 0.f, 0.f);
    if (ch < 25) {
        int pe = perm[r];
        v = *(const float4*)(edge_attr + (size_t)pe * G + ch * 4);
    }
    uint2 p; p.x = pack2(v.x, v.y); p.y = pack2(v.z, v.w);
    *(uint2*)(attr_p + (size_t)r * 128 + ch * 4) = p;
}

// ---------------------------------------------------------------------------
// Fused edge MLP — EXACT R6 configuration (empirical optimum: 122 us).
// 2-wave cooperative ct-split, 32 edges per 128-thread block.
// Ledger R4/R6/R7/R8: edge dur vs occupancy = 141@21% / 122@40% / 151@17% /
// 139@81% -> occupancy is NOT the binder beyond ~40%; 4-way split's
// duplicated attr reads + halved per-wave ILP regressed it. 2-wave is the
// sweet spot. NO min-waves hint (R2/R3: caps below natural demand = spill).
__global__ __launch_bounds__(128) void edge_mlp_kernel(
    const ushort_t* __restrict__ attr_p, const float* __restrict__ cm_p,
    const ushort_t* __restrict__ w1b, const float* __restrict__ b1,
    const ushort_t* __restrict__ w2b, const float* __restrict__ b2,
    ushort_t* __restrict__ wf) {
    __shared__ __align__(16) ushort_t sT[32][136];

    int t = threadIdx.x, lane = t & 63, wid = t >> 6;
    int c = lane & 15, quad = lane >> 4;
    int er0 = blockIdx.x * 32;
    int mbase = wid * 64;   // this wave's output-column base

    f32x4 acc[2][4];
#pragma unroll
    for (int st = 0; st < 2; ++st)
#pragma unroll
        for (int ct = 0; ct < 4; ++ct) acc[st][ct] = (f32x4){0.f, 0.f, 0.f, 0.f};

    // GEMM1 (A = this wave's W1 half, L2-hot; B = attr_p strips, L2/L3-hot)
#pragma unroll
    for (int ks = 0; ks < 4; ++ks) {
        int koff = ks * 32 + quad * 8;
        bf16x8 b0  = *(const bf16x8*)(attr_p + (size_t)(er0 + c) * 128 + koff);
        bf16x8 b1v = *(const bf16x8*)(attr_p + (size_t)(er0 + 16 + c) * 128 + koff);
#pragma unroll
        for (int ct = 0; ct < 4; ++ct) {
            bf16x8 a = *(const bf16x8*)(w1b + (size_t)(mbase + ct * 16 + c) * 128 + koff);
            acc[0][ct] = mfma_bf16(a, b0, acc[0][ct]);
            acc[1][ct] = mfma_bf16(a, b1v, acc[1][ct]);
        }
    }
    // epilogue1: u = ssp(acc + b1) -> sT cols [mbase, mbase+64)
#pragma unroll
    for (int st = 0; st < 2; ++st)
#pragma unroll
        for (int ct = 0; ct < 4; ++ct) {
            int col = mbase + ct * 16 + quad * 4;
            float4 bv = *(const float4*)(b1 + col);
            uint2 p;
            p.x = pack2(sspf(acc[st][ct][0] + bv.x), sspf(acc[st][ct][1] + bv.y));
            p.y = pack2(sspf(acc[st][ct][2] + bv.z), sspf(acc[st][ct][3] + bv.w));
            *(uint2*)(&sT[st * 16 + c][col]) = p;
        }

    __syncthreads();   // both waves' u halves complete before K-sweep

    // GEMM2 (B = full-K u rows from LDS; A = this wave's W2 half)
#pragma unroll
    for (int st = 0; st < 2; ++st)
#pragma unroll
        for (int ct = 0; ct < 4; ++ct) acc[st][ct] = (f32x4){0.f, 0.f, 0.f, 0.f};
#pragma unroll
    for (int ks = 0; ks < 4; ++ks) {
        int koff = ks * 32 + quad * 8;
        bf16x8 b0  = *(const bf16x8*)(&sT[c][koff]);
        bf16x8 b1v = *(const bf16x8*)(&sT[16 + c][koff]);
#pragma unroll
        for (int ct = 0; ct < 4; ++ct) {
            bf16x8 a = *(const bf16x8*)(w2b + (size_t)(mbase + ct * 16 + c) * 128 + koff);
            acc[0][ct] = mfma_bf16(a, b0, acc[0][ct]);
            acc[1][ct] = mfma_bf16(a, b1v, acc[1][ct]);
        }
    }
    // epilogue2: Wf = (acc + b2) * C -> direct 8B global stores
#pragma unroll
    for (int st = 0; st < 2; ++st) {
        int e = er0 + st * 16 + c;
        float cv = cm_p[e];
#pragma unroll
        for (int ct = 0; ct < 4; ++ct) {
            int col = mbase + ct * 16 + quad * 4;
            float4 bv = *(const float4*)(b2 + col);
            uint2 p;
            p.x = pack2((acc[st][ct][0] + bv.x) * cv, (acc[st][ct][1] + bv.y) * cv);
            p.y = pack2((acc[st][ct][2] + bv.z) * cv, (acc[st][ct][3] + bv.w) * cv);
            *(uint2*)(wf + (size_t)e * 128 + col) = p;
        }
    }
}

// ---------------------------------------------------------------------------
// Node GEMM (used only for lin1 now), FOUR-wave ct-split; 32 nodes per
// 256-thread block (grid 625). R8 showed the 4-wave node config improved the
// tail ~60 us vs 2-wave. out[node][col] = W . in^T, bf16 out.
__global__ __launch_bounds__(256) void lin1_kernel(
    const float* __restrict__ in0, const ushort_t* __restrict__ Wb,
    ushort_t* __restrict__ outp) {
    __shared__ __align__(16) ushort_t sT[32][136];
    int t = threadIdx.x, lane = t & 63, wid = t >> 6;   // wid 0..3
    int c = lane & 15, quad = lane >> 4;
    int n0 = blockIdx.x * 32;
    int mbase = wid * 32;

    f32x4 acc[2][2];
#pragma unroll
    for (int st = 0; st < 2; ++st)
#pragma unroll
        for (int ct = 0; ct < 2; ++ct) acc[st][ct] = (f32x4){0.f, 0.f, 0.f, 0.f};

    // stage 32 rows fp32 -> bf16 LDS (4 iters x 256 threads = 32r x 32ch)
#pragma unroll
    for (int i = 0; i < 4; ++i) {
        int idx = i * 256 + t;
        int r = idx >> 5, ch = idx & 31;
        int gr = n0 + r;
        float4 v = make_float4(0.f, 0.f, 0.f, 0.f);
        if (gr < N_NODES) v = *(const float4*)(in0 + (size_t)gr * 128 + ch * 4);
        uint2 p; p.x = pack2(v.x, v.y); p.y = pack2(v.z, v.w);
        *(uint2*)(&sT[r][ch * 4]) = p;
    }
    __syncthreads();
#pragma unroll
    for (int ks = 0; ks < 4; ++ks) {
        int koff = ks * 32 + quad * 8;
        bf16x8 b0  = *(const bf16x8*)(&sT[c][koff]);
        bf16x8 b1v = *(const bf16x8*)(&sT[16 + c][koff]);
#pragma unroll
        for (int ct = 0; ct < 2; ++ct) {
            bf16x8 a = *(const bf16x8*)(Wb + (size_t)(mbase + ct * 16 + c) * 128 + koff);
            acc[0][ct] = mfma_bf16(a, b0, acc[0][ct]);
            acc[1][ct] = mfma_bf16(a, b1v, acc[1][ct]);
        }
    }

#pragma unroll
    for (int st = 0; st < 2; ++st) {
        int node = n0 + st * 16 + c;
        if (node < N_NODES) {
#pragma unroll
            for (int ct = 0; ct < 2; ++ct) {
                int col = mbase + ct * 16 + quad * 4;
                uint2 p;
                p.x = pack2(acc[st][ct][0], acc[st][ct][1]);
                p.y = pack2(acc[st][ct][2], acc[st][ct][3]);
                *(uint2*)(outp + (size_t)node * 128 + col) = p;
            }
        }
    }
}

// ---------------------------------------------------------------------------
// Fused lin2+update tail, FOUR-wave ct-split, 32 nodes/block (grid 625):
//   phase 1: m = ssp(lin2 . m_i^T + b2)            (m kept in LDS bf16)
//   phase 2: h += lin_w . concat(h, m)^T + bu      (K=256: h from sT, m from sM)
// Removes the m fp32 HBM round-trip (20 MB/layer) + one dispatch boundary.
// Same rounding as the split path: m packed to bf16 exactly where the old
// update kernel's staging did. In-place h safe: block reads only its rows.
__global__ __launch_bounds__(256) void fused_tail_kernel(
    const float* __restrict__ m_in, const float* __restrict__ h,
    const ushort_t* __restrict__ W2b, const float* __restrict__ b2,
    const ushort_t* __restrict__ Wub, const float* __restrict__ bu,
    float* __restrict__ h_out) {
    __shared__ __align__(16) ushort_t sT[32][136];
    __shared__ __align__(16) ushort_t sM[32][136];
    int t = threadIdx.x, lane = t & 63, wid = t >> 6;   // wid 0..3
    int c = lane & 15, quad = lane >> 4;
    int n0 = blockIdx.x * 32;
    int mbase = wid * 32;

    f32x4 acc[2][2];
#pragma unroll
    for (int st = 0; st < 2; ++st)
#pragma unroll
        for (int ct = 0; ct < 2; ++ct) acc[st][ct] = (f32x4){0.f, 0.f, 0.f, 0.f};

    // ---- phase 1: stage m_i fp32 -> bf16 sT
#pragma unroll
    for (int i = 0; i < 4; ++i) {
        int idx = i * 256 + t;
        int r = idx >> 5, ch = idx & 31;
        int gr = n0 + r;
        float4 v = make_float4(0.f, 0.f, 0.f, 0.f);
        if (gr < N_NODES) v = *(const float4*)(m_in + (size_t)gr * 128 + ch * 4);
        uint2 p; p.x = pack2(v.x, v.y); p.y = pack2(v.z, v.w);
        *(uint2*)(&sT[r][ch * 4]) = p;
    }
    __syncthreads();
    // lin2 GEMM
#pragma unroll
    for (int ks = 0; ks < 4; ++ks) {
        int koff = ks * 32 + quad * 8;
        bf16x8 b0  = *(const bf16x8*)(&sT[c][koff]);
        bf16x8 b1v = *(const bf16x8*)(&sT[16 + c][koff]);
#pragma unroll
        for (int ct = 0; ct < 2; ++ct) {
            bf16x8 a = *(const bf16x8*)(W2b + (size_t)(mbase + ct * 16 + c) * 128 + koff);
            acc[0][ct] = mfma_bf16(a, b0, acc[0][ct]);
            acc[1][ct] = mfma_bf16(a, b1v, acc[1][ct]);
        }
    }
    // m = ssp(acc + b2) -> sM cols [mbase, mbase+32)
#pragma unroll
    for (int st = 0; st < 2; ++st)
#pragma unroll
        for (int ct = 0; ct < 2; ++ct) {
            int col = mbase + ct * 16 + quad * 4;
            float4 bv = *(const float4*)(b2 + col);
            uint2 p;
            p.x = pack2(sspf(acc[st][ct][0] + bv.x), sspf(acc[st][ct][1] + bv.y));
            p.y = pack2(sspf(acc[st][ct][2] + bv.z), sspf(acc[st][ct][3] + bv.w));
            *(uint2*)(&sM[st * 16 + c][col]) = p;
        }
    __syncthreads();   // sM complete; all GEMM reads of sT done -> safe to restage

    // ---- phase 2: stage h fp32 -> bf16 sT
#pragma unroll
    for (int i = 0; i < 4; ++i) {
        int idx = i * 256 + t;
        int r = idx >> 5, ch = idx & 31;
        int gr = n0 + r;
        float4 v = make_float4(0.f, 0.f, 0.f, 0.f);
        if (gr < N_NODES) v = *(const float4*)(h + (size_t)gr * 128 + ch * 4);
        uint2 p; p.x = pack2(v.x, v.y); p.y = pack2(v.z, v.w);
        *(uint2*)(&sT[r][ch * 4]) = p;
    }
    __syncthreads();
    // update GEMM, K=256: k in [0,128) from h (sT), [128,256) from m (sM)
#pragma unroll
    for (int st = 0; st < 2; ++st)
#pragma unroll
        for (int ct = 0; ct < 2; ++ct) acc[st][ct] = (f32x4){0.f, 0.f, 0.f, 0.f};
#pragma unroll
    for (int ks = 0; ks < 4; ++ks) {
        int koff = ks * 32 + quad * 8;
        bf16x8 b0  = *(const bf16x8*)(&sT[c][koff]);
        bf16x8 b1v = *(const bf16x8*)(&sT[16 + c][koff]);
#pragma unroll
        for (int ct = 0; ct < 2; ++ct) {
            bf16x8 a = *(const bf16x8*)(Wub + (size_t)(mbase + ct * 16 + c) * 256 + koff);
            acc[0][ct] = mfma_bf16(a, b0, acc[0][ct]);
            acc[1][ct] = mfma_bf16(a, b1v, acc[1][ct]);
        }
    }
#pragma unroll
    for (int ks = 0; ks < 4; ++ks) {
        int koff = ks * 32 + quad * 8;
        bf16x8 b0  = *(const bf16x8*)(&sM[c][koff]);
        bf16x8 b1v = *(const bf16x8*)(&sM[16 + c][koff]);
#pragma unroll
        for (int ct = 0; ct < 2; ++ct) {
            bf16x8 a = *(const bf16x8*)(Wub + (size_t)(mbase + ct * 16 + c) * 256 + 128 + koff);
            acc[0][ct] = mfma_bf16(a, b0, acc[0][ct]);
            acc[1][ct] = mfma_bf16(a, b1v, acc[1][ct]);
        }
    }
    // epilogue: h_out = acc + bu + h (resid)
#pragma unroll
    for (int st = 0; st < 2; ++st) {
        int node = n0 + st * 16 + c;
        if (node < N_NODES) {
#pragma unroll
            for (int ct = 0; ct < 2; ++ct) {
                int col = mbase + ct * 16 + quad * 4;
                float4 bv = *(const float4*)(bu + col);
                float4 rv = *(const float4*)(h + (size_t)node * 128 + col);
                float4 o;
                o.x = acc[st][ct][0] + bv.x + rv.x;
                o.y = acc[st][ct][1] + bv.y + rv.y;
                o.z = acc[st][ct][2] + bv.z + rv.z;
                o.w = acc[st][ct][3] + bv.w + rv.w;
                *(float4*)(h_out + (size_t)node * 128 + col) = o;
            }
        }
    }
}

// ---------------------------------------------------------------------------
// Segment sum: one wave per dst node, 2 cols/lane; wf and xf both bf16.
__global__ __launch_bounds__(256) void segsum_kernel(
    const ushort_t* __restrict__ wf, const ushort_t* __restrict__ xf_bf,
    const int* __restrict__ row_start, const int* __restrict__ src_p,
    float* __restrict__ m_i) {
    int t = threadIdx.x, lane = t & 63;
    int n = blockIdx.x * 4 + (t >> 6);
    int beg = row_start[n], end = row_start[n + 1];
    float a0 = 0.f, a1 = 0.f;
    for (int i = beg; i < end; ++i) {
        uint_t w = *(const uint_t*)(wf + (size_t)i * 128 + lane * 2);
        uint_t x = *(const uint_t*)(xf_bf + (size_t)src_p[i] * 128 + lane * 2);
        a0 += __uint_as_float(w << 16) * __uint_as_float(x << 16);
        a1 += __uint_as_float(w & 0xffff0000u) * __uint_as_float(x & 0xffff0000u);
    }
    *(float2*)(m_i + (size_t)n * 128 + lane * 2) = make_float2(a0, a1);
}

// ---------------------------------------------------------------------------
extern "C" void kernel_launch(void* const* d_in, const int* in_sizes, int n_in,
                              void* d_out, int out_size, void* d_ws, size_t ws_size,
                              hipStream_t stream) {
    const float* z        = (const float*)d_in[0];
    const int*   ei       = (const int*)d_in[1];
    const float* el       = (const float*)d_in[2];
    const float* ea       = (const float*)d_in[3];
    const float* emblin_w = (const float*)d_in[4];
    const float* emblin_b = (const float*)d_in[5];
    const float* mlp_w1   = (const float*)d_in[6];
    const float* mlp_b1   = (const float*)d_in[7];
    const float* mlp_w2   = (const float*)d_in[8];
    const float* mlp_b2   = (const float*)d_in[9];
    const float* lin1_w   = (const float*)d_in[10];
    const float* lin2_w   = (const float*)d_in[11];
    const float* lin2_b   = (const float*)d_in[12];
    const float* lin_w    = (const float*)d_in[13];
    const float* lin_b    = (const float*)d_in[14];
    (void)in_sizes; (void)n_in; (void)out_size; (void)ws_size;

    const size_t ND = (size_t)N_NODES * D;
    float* ws   = (float*)d_ws;
    float* h    = ws;                // N*D fp32
    float* m_i  = h + ND;            // N*D fp32
    float* cm_p = m_i + ND;          // E fp32 (cutoff mask, CSR-permuted)
    float* fend = cm_p + E_EDGES;

    ushort_t* w1b    = (ushort_t*)fend;                     // L*D*128
    ushort_t* w2b    = w1b   + (size_t)L_LAYERS * D * 128;  // L*D*D
    ushort_t* lin1b  = w2b   + (size_t)L_LAYERS * D * D;    // L*D*D
    ushort_t* lin2b  = lin1b + (size_t)L_LAYERS * D * D;    // L*D*D
    ushort_t* linwb  = lin2b + (size_t)L_LAYERS * D * D;    // L*D*256
    ushort_t* wf     = linwb + (size_t)L_LAYERS * D * 256;  // E*128
    ushort_t* xf_bf  = wf    + (size_t)E_EDGES * 128;       // N*128
    ushort_t* attr_p = xf_bf + ND;                          // E*128 (bf16, permuted, k-padded)
    int* ibase      = (int*)(attr_p + (size_t)E_EDGES * 128);
    int* deg        = ibase;                 // N
    int* row_start  = deg + N_NODES;         // N+1
    int* cursor     = row_start + N_NODES + 1;
    int* perm       = cursor + N_NODES;      // E
    int* src_p      = perm + E_EDGES;        // E

    // one-time weight prep (all bf16, row-major [out][k] = A-fragment layout)
    convw1_kernel<<<(L_LAYERS * D * 128) / 256, 256, 0, stream>>>(mlp_w1, w1b);
    castbf_kernel<<<(L_LAYERS * D * D) / 256, 256, 0, stream>>>(mlp_w2, w2b);
    castbf_kernel<<<(L_LAYERS * D * D) / 256, 256, 0, stream>>>(lin1_w, lin1b);
    castbf_kernel<<<(L_LAYERS * D * D) / 256, 256, 0, stream>>>(lin2_w, lin2b);
    castbf_kernel<<<(L_LAYERS * D * 256) / 256, 256, 0, stream>>>(lin_w, linwb);

    // CSR build
    hipMemsetAsync(deg, 0, (size_t)N_NODES * sizeof(int), stream);
    hist_kernel<<<E_EDGES / 256, 256, 0, stream>>>(ei, deg);
    scan_kernel<<<1, 1024, 0, stream>>>(deg, row_start, cursor);
    scatter_perm_kernel<<<E_EDGES / 256, 256, 0, stream>>>(ei, el, cursor, perm, src_p, cm_p);
    // one-time attr gather->bf16->permuted (hoisted out of the layer loop)
    attr_perm_kernel<<<(E_EDGES * 32) / 256, 256, 0, stream>>>(ea, perm, attr_p);

    embed_kernel<<<N_NODES, D, 0, stream>>>(z, emblin_w, emblin_b, h);

    const int NBLK = (N_NODES + 31) / 32;   // 625
    for (int l = 0; l < L_LAYERS; ++l) {
        // xf_bf = h @ lin1^T   (bf16 out, no bias)
        lin1_kernel<<<NBLK, 256, 0, stream>>>(h, lin1b + (size_t)l * D * D, xf_bf);
        edge_mlp_kernel<<<E_EDGES / 32, 128, 0, stream>>>(
            attr_p, cm_p, w1b + (size_t)l * D * 128, mlp_b1 + (size_t)l * D,
            w2b + (size_t)l * D * D, mlp_b2 + (size_t)l * D, wf);
        segsum_kernel<<<N_NODES / 4, 256, 0, stream>>>(wf, xf_bf, row_start, src_p, m_i);
        // fused: m = ssp(m_i@lin2^T+b);  h = h + concat(h,m)@lin_w^T + b
        fused_tail_kernel<<<NBLK, 256, 0, stream>>>(
            m_i, h, lin2b + (size_t)l * D * D, lin2_b + (size_t)l * D,
            linwb + (size_t)l * D * 256, lin_b + (size_t)l * D, h);
    }

    hipMemcpyAsync(d_out, h, ND * sizeof(float), hipMemcpyDeviceToDevice, stream);
}

// Round 11
// 1304.250 us; speedup vs baseline: 1.2605x; 1.0739x over previous
//
#include <hip/hip_runtime.h>

#define N_NODES 20000
#define D 128
#define E_EDGES 320000
#define G 100
#define L_LAYERS 6
#define IN_DIM 5
#define ZROW (IN_DIM + D)
#define CUTOFF_V 10.0f
#define LOG2F_ 0.69314718055994530942f

typedef __attribute__((ext_vector_type(8))) short bf16x8;
typedef __attribute__((ext_vector_type(4))) float f32x4;
typedef unsigned short ushort_t;
typedef unsigned int uint_t;

__device__ __forceinline__ float sspf(float x) {
    // softplus(x)-log2 via fast hw exp/log (log arg in (1,2], well conditioned)
    return fmaxf(x, 0.0f) + __logf(1.0f + __expf(-fabsf(x))) - LOG2F_;
}

__device__ __forceinline__ ushort_t f2bf(float f) {
    union { float f; uint_t u; } x; x.f = f;
    uint_t r = ((x.u >> 16) & 1u) + 0x7fffu;
    return (ushort_t)((x.u + r) >> 16);
}

__device__ __forceinline__ uint_t pack2(float a, float b) {
    return (uint_t)f2bf(a) | ((uint_t)f2bf(b) << 16);
}

__device__ __forceinline__ float bf16lo(uint_t u) { return __uint_as_float(u << 16); }
__device__ __forceinline__ float bf16hi(uint_t u) { return __uint_as_float(u & 0xffff0000u); }

__device__ __forceinline__ f32x4 mfma_bf16(bf16x8 a, bf16x8 b, f32x4 c) {
    return __builtin_amdgcn_mfma_f32_16x16x32_bf16(a, b, c, 0, 0, 0);
}

// ---------------------------------------------------------------------------
__global__ void embed_kernel(const float* __restrict__ z,
                             const float* __restrict__ ew,
                             const float* __restrict__ eb,
                             float* __restrict__ h) {
    int n = blockIdx.x;
    int d = threadIdx.x;
    const float* zr = z + (size_t)n * ZROW;
    float acc = eb[d] + zr[IN_DIM + d];
#pragma unroll
    for (int k = 0; k < IN_DIM; ++k) acc += zr[k] * ew[d * IN_DIM + k];
    h[(size_t)n * D + d] = acc;
}

// ---------------------------------------------------------------------------
// mlp_w1 [L][D][G] -> bf16 [L][D][128] zero-padded in k
__global__ void convw1_kernel(const float* __restrict__ w1, ushort_t* __restrict__ out) {
    int idx = blockIdx.x * 256 + threadIdx.x;
    int k = idx & 127;
    int nl = idx >> 7;
    out[idx] = (k < G) ? f2bf(w1[(size_t)nl * G + k]) : (ushort_t)0;
}

__global__ void castbf_kernel(const float* __restrict__ src, ushort_t* __restrict__ dst) {
    int i = blockIdx.x * 256 + threadIdx.x;
    dst[i] = f2bf(src[i]);
}

// ---------------------------------------------------------------------------
// CSR build (edge graph constant across layers)
__global__ void hist_kernel(const int* __restrict__ ei, int* __restrict__ deg) {
    int e = blockIdx.x * 256 + threadIdx.x;
    atomicAdd(&deg[ei[E_EDGES + e]], 1);
}

__global__ __launch_bounds__(1024) void scan_kernel(const int* __restrict__ deg,
                                                    int* __restrict__ row_start,
                                                    int* __restrict__ cursor) {
    __shared__ int wsum[16];
    int t = threadIdx.x;
    const int CH = (N_NODES + 1023) / 1024;
    int base = t * CH;
    int s = 0;
    for (int i = 0; i < CH; ++i) {
        int idx = base + i;
        if (idx < N_NODES) s += deg[idx];
    }
    int lane = t & 63, wid = t >> 6;
    int v = s;
    for (int o = 1; o < 64; o <<= 1) {
        int u = __shfl_up(v, o, 64);
        if (lane >= o) v += u;
    }
    if (lane == 63) wsum[wid] = v;
    __syncthreads();
    if (t == 0) {
        int acc = 0;
        for (int i = 0; i < 16; ++i) { int tmp = wsum[i]; wsum[i] = acc; acc += tmp; }
    }
    __syncthreads();
    int run = v - s + wsum[wid];
    for (int i = 0; i < CH; ++i) {
        int idx = base + i;
        if (idx < N_NODES) {
            row_start[idx] = run;
            cursor[idx] = run;
            run += deg[idx];
        }
    }
    if (t == 0) row_start[N_NODES] = E_EDGES;
}

__global__ void scatter_perm_kernel(const int* __restrict__ ei, const float* __restrict__ el,
                                    int* __restrict__ cursor,
                                    int* __restrict__ perm, int* __restrict__ src_p,
                                    float* __restrict__ cm_p) {
    int e = blockIdx.x * 256 + threadIdx.x;
    int d = ei[E_EDGES + e];
    int p = atomicAdd(&cursor[d], 1);
    perm[p] = e;
    src_p[p] = ei[e];
    cm_p[p] = (el[e] <= CUTOFF_V) ? 1.0f : 0.0f;
}

// ---------------------------------------------------------------------------
// One-time: gather edge_attr rows into CSR-permuted, bf16, k-padded-to-128
// layout. 32 lanes per row (25 active float4 chunks), fully coalesced writes.
__global__ void attr_perm_kernel(const float* __restrict__ edge_attr,
                                 const int* __restrict__ perm,
                                 ushort_t* __restrict__ attr_p) {
    int tid = blockIdx.x * 256 + threadIdx.x;
    int r = tid >> 5, ch = tid & 31;
    float4 v = make_float4(0.f, 0.f, 0.f, 0.f);
    if (ch < 25) {
        int pe = perm[r];
        v = *(const float4*)(edge_attr + (size_t)pe * G + ch * 4);
    }
    uint2 p; p.x = pack2(v.x, v.y); p.y = pack2(v.z, v.w);
    *(uint2*)(attr_p + (size_t)r * 128 + ch * 4) = p;
}

// ---------------------------------------------------------------------------
// Fused edge MLP — EXACT R6 configuration (empirical optimum: 122 us).
// 2-wave cooperative ct-split, 32 edges per 128-thread block. CONTROL this
// round — untouched. Ledger R4/R6/R7/R8: 141@21% / 122@40% / 151@17% /
// 139@81% -> occupancy not the binder past ~40%; register prefetch loses.
__global__ __launch_bounds__(128) void edge_mlp_kernel(
    const ushort_t* __restrict__ attr_p, const float* __restrict__ cm_p,
    const ushort_t* __restrict__ w1b, const float* __restrict__ b1,
    const ushort_t* __restrict__ w2b, const float* __restrict__ b2,
    ushort_t* __restrict__ wf) {
    __shared__ __align__(16) ushort_t sT[32][136];

    int t = threadIdx.x, lane = t & 63, wid = t >> 6;
    int c = lane & 15, quad = lane >> 4;
    int er0 = blockIdx.x * 32;
    int mbase = wid * 64;   // this wave's output-column base

    f32x4 acc[2][4];
#pragma unroll
    for (int st = 0; st < 2; ++st)
#pragma unroll
        for (int ct = 0; ct < 4; ++ct) acc[st][ct] = (f32x4){0.f, 0.f, 0.f, 0.f};

    // GEMM1 (A = this wave's W1 half, L2-hot; B = attr_p strips, L2/L3-hot)
#pragma unroll
    for (int ks = 0; ks < 4; ++ks) {
        int koff = ks * 32 + quad * 8;
        bf16x8 b0  = *(const bf16x8*)(attr_p + (size_t)(er0 + c) * 128 + koff);
        bf16x8 b1v = *(const bf16x8*)(attr_p + (size_t)(er0 + 16 + c) * 128 + koff);
#pragma unroll
        for (int ct = 0; ct < 4; ++ct) {
            bf16x8 a = *(const bf16x8*)(w1b + (size_t)(mbase + ct * 16 + c) * 128 + koff);
            acc[0][ct] = mfma_bf16(a, b0, acc[0][ct]);
            acc[1][ct] = mfma_bf16(a, b1v, acc[1][ct]);
        }
    }
    // epilogue1: u = ssp(acc + b1) -> sT cols [mbase, mbase+64)
#pragma unroll
    for (int st = 0; st < 2; ++st)
#pragma unroll
        for (int ct = 0; ct < 4; ++ct) {
            int col = mbase + ct * 16 + quad * 4;
            float4 bv = *(const float4*)(b1 + col);
            uint2 p;
            p.x = pack2(sspf(acc[st][ct][0] + bv.x), sspf(acc[st][ct][1] + bv.y));
            p.y = pack2(sspf(acc[st][ct][2] + bv.z), sspf(acc[st][ct][3] + bv.w));
            *(uint2*)(&sT[st * 16 + c][col]) = p;
        }

    __syncthreads();   // both waves' u halves complete before K-sweep

    // GEMM2 (B = full-K u rows from LDS; A = this wave's W2 half)
#pragma unroll
    for (int st = 0; st < 2; ++st)
#pragma unroll
        for (int ct = 0; ct < 4; ++ct) acc[st][ct] = (f32x4){0.f, 0.f, 0.f, 0.f};
#pragma unroll
    for (int ks = 0; ks < 4; ++ks) {
        int koff = ks * 32 + quad * 8;
        bf16x8 b0  = *(const bf16x8*)(&sT[c][koff]);
        bf16x8 b1v = *(const bf16x8*)(&sT[16 + c][koff]);
#pragma unroll
        for (int ct = 0; ct < 4; ++ct) {
            bf16x8 a = *(const bf16x8*)(w2b + (size_t)(mbase + ct * 16 + c) * 128 + koff);
            acc[0][ct] = mfma_bf16(a, b0, acc[0][ct]);
            acc[1][ct] = mfma_bf16(a, b1v, acc[1][ct]);
        }
    }
    // epilogue2: Wf = (acc + b2) * C -> direct 8B global stores
#pragma unroll
    for (int st = 0; st < 2; ++st) {
        int e = er0 + st * 16 + c;
        float cv = cm_p[e];
#pragma unroll
        for (int ct = 0; ct < 4; ++ct) {
            int col = mbase + ct * 16 + quad * 4;
            float4 bv = *(const float4*)(b2 + col);
            uint2 p;
            p.x = pack2((acc[st][ct][0] + bv.x) * cv, (acc[st][ct][1] + bv.y) * cv);
            p.y = pack2((acc[st][ct][2] + bv.z) * cv, (acc[st][ct][3] + bv.w) * cv);
            *(uint2*)(wf + (size_t)e * 128 + col) = p;
        }
    }
}

// ---------------------------------------------------------------------------
// Standalone lin1 (used ONLY for layer 0, from embed's h). FOUR-wave
// ct-split; 32 nodes per 256-thread block. out = bf16(h @ W^T).
__global__ __launch_bounds__(256) void lin1_kernel(
    const float* __restrict__ in0, const ushort_t* __restrict__ Wb,
    ushort_t* __restrict__ outp) {
    __shared__ __align__(16) ushort_t sT[32][136];
    int t = threadIdx.x, lane = t & 63, wid = t >> 6;   // wid 0..3
    int c = lane & 15, quad = lane >> 4;
    int n0 = blockIdx.x * 32;
    int mbase = wid * 32;

    f32x4 acc[2][2];
#pragma unroll
    for (int st = 0; st < 2; ++st)
#pragma unroll
        for (int ct = 0; ct < 2; ++ct) acc[st][ct] = (f32x4){0.f, 0.f, 0.f, 0.f};

    // stage 32 rows fp32 -> bf16 LDS (4 iters x 256 threads = 32r x 32ch)
#pragma unroll
    for (int i = 0; i < 4; ++i) {
        int idx = i * 256 + t;
        int r = idx >> 5, ch = idx & 31;
        int gr = n0 + r;
        float4 v = make_float4(0.f, 0.f, 0.f, 0.f);
        if (gr < N_NODES) v = *(const float4*)(in0 + (size_t)gr * 128 + ch * 4);
        uint2 p; p.x = pack2(v.x, v.y); p.y = pack2(v.z, v.w);
        *(uint2*)(&sT[r][ch * 4]) = p;
    }
    __syncthreads();
#pragma unroll
    for (int ks = 0; ks < 4; ++ks) {
        int koff = ks * 32 + quad * 8;
        bf16x8 b0  = *(const bf16x8*)(&sT[c][koff]);
        bf16x8 b1v = *(const bf16x8*)(&sT[16 + c][koff]);
#pragma unroll
        for (int ct = 0; ct < 2; ++ct) {
            bf16x8 a = *(const bf16x8*)(Wb + (size_t)(mbase + ct * 16 + c) * 128 + koff);
            acc[0][ct] = mfma_bf16(a, b0, acc[0][ct]);
            acc[1][ct] = mfma_bf16(a, b1v, acc[1][ct]);
        }
    }

#pragma unroll
    for (int st = 0; st < 2; ++st) {
        int node = n0 + st * 16 + c;
        if (node < N_NODES) {
#pragma unroll
            for (int ct = 0; ct < 2; ++ct) {
                int col = mbase + ct * 16 + quad * 4;
                uint2 p;
                p.x = pack2(acc[st][ct][0], acc[st][ct][1]);
                p.y = pack2(acc[st][ct][2], acc[st][ct][3]);
                *(uint2*)(outp + (size_t)node * 128 + col) = p;
            }
        }
    }
}

// ---------------------------------------------------------------------------
// Fused lin2+update(+next-layer lin1) tail, FOUR-wave ct-split, 32 nodes/blk:
//   phase 1: m = ssp(lin2 . m_i^T + b2)            (m kept in LDS bf16, sM)
//   phase 2: hn = h + lin_w . concat(h, m)^T + bu  (K=256: h via sT, m via sM)
//   phase 3 (DOLIN1): xf = hn @ lin1[l+1]^T        (hn packed to sT from regs
//                                                   — same rounding as the old
//                                                   lin1 kernel's staging)
// Removes the m fp32 round-trip AND (for l>=1) lin1's h re-read + restage.
// Barrier before the hn->sT overwrite orders it after all update-GEMM reads.
template <bool DOLIN1>
__global__ __launch_bounds__(256) void fused_tail_kernel(
    const float* __restrict__ m_in, const float* __restrict__ h,
    const ushort_t* __restrict__ W2b, const float* __restrict__ b2,
    const ushort_t* __restrict__ Wub, const float* __restrict__ bu,
    const ushort_t* __restrict__ lin1n, float* __restrict__ h_out,
    ushort_t* __restrict__ xf_out) {
    __shared__ __align__(16) ushort_t sT[32][136];
    __shared__ __align__(16) ushort_t sM[32][136];
    int t = threadIdx.x, lane = t & 63, wid = t >> 6;   // wid 0..3
    int c = lane & 15, quad = lane >> 4;
    int n0 = blockIdx.x * 32;
    int mbase = wid * 32;

    f32x4 acc[2][2];
#pragma unroll
    for (int st = 0; st < 2; ++st)
#pragma unroll
        for (int ct = 0; ct < 2; ++ct) acc[st][ct] = (f32x4){0.f, 0.f, 0.f, 0.f};

    // ---- phase 1: stage m_i fp32 -> bf16 sT
#pragma unroll
    for (int i = 0; i < 4; ++i) {
        int idx = i * 256 + t;
        int r = idx >> 5, ch = idx & 31;
        int gr = n0 + r;
        float4 v = make_float4(0.f, 0.f, 0.f, 0.f);
        if (gr < N_NODES) v = *(const float4*)(m_in + (size_t)gr * 128 + ch * 4);
        uint2 p; p.x = pack2(v.x, v.y); p.y = pack2(v.z, v.w);
        *(uint2*)(&sT[r][ch * 4]) = p;
    }
    __syncthreads();
    // lin2 GEMM
#pragma unroll
    for (int ks = 0; ks < 4; ++ks) {
        int koff = ks * 32 + quad * 8;
        bf16x8 b0  = *(const bf16x8*)(&sT[c][koff]);
        bf16x8 b1v = *(const bf16x8*)(&sT[16 + c][koff]);
#pragma unroll
        for (int ct = 0; ct < 2; ++ct) {
            bf16x8 a = *(const bf16x8*)(W2b + (size_t)(mbase + ct * 16 + c) * 128 + koff);
            acc[0][ct] = mfma_bf16(a, b0, acc[0][ct]);
            acc[1][ct] = mfma_bf16(a, b1v, acc[1][ct]);
        }
    }
    // m = ssp(acc + b2) -> sM cols [mbase, mbase+32)
#pragma unroll
    for (int st = 0; st < 2; ++st)
#pragma unroll
        for (int ct = 0; ct < 2; ++ct) {
            int col = mbase + ct * 16 + quad * 4;
            float4 bv = *(const float4*)(b2 + col);
            uint2 p;
            p.x = pack2(sspf(acc[st][ct][0] + bv.x), sspf(acc[st][ct][1] + bv.y));
            p.y = pack2(sspf(acc[st][ct][2] + bv.z), sspf(acc[st][ct][3] + bv.w));
            *(uint2*)(&sM[st * 16 + c][col]) = p;
        }
    __syncthreads();   // sM complete; all GEMM reads of sT done -> safe to restage

    // ---- phase 2: stage h fp32 -> bf16 sT
#pragma unroll
    for (int i = 0; i < 4; ++i) {
        int idx = i * 256 + t;
        int r = idx >> 5, ch = idx & 31;
        int gr = n0 + r;
        float4 v = make_float4(0.f, 0.f, 0.f, 0.f);
        if (gr < N_NODES) v = *(const float4*)(h + (size_t)gr * 128 + ch * 4);
        uint2 p; p.x = pack2(v.x, v.y); p.y = pack2(v.z, v.w);
        *(uint2*)(&sT[r][ch * 4]) = p;
    }
    __syncthreads();
    // update GEMM, K=256: k in [0,128) from h (sT), [128,256) from m (sM)
#pragma unroll
    for (int st = 0; st < 2; ++st)
#pragma unroll
        for (int ct = 0; ct < 2; ++ct) acc[st][ct] = (f32x4){0.f, 0.f, 0.f, 0.f};
#pragma unroll
    for (int ks = 0; ks < 4; ++ks) {
        int koff = ks * 32 + quad * 8;
        bf16x8 b0  = *(const bf16x8*)(&sT[c][koff]);
        bf16x8 b1v = *(const bf16x8*)(&sT[16 + c][koff]);
#pragma unroll
        for (int ct = 0; ct < 2; ++ct) {
            bf16x8 a = *(const bf16x8*)(Wub + (size_t)(mbase + ct * 16 + c) * 256 + koff);
            acc[0][ct] = mfma_bf16(a, b0, acc[0][ct]);
            acc[1][ct] = mfma_bf16(a, b1v, acc[1][ct]);
        }
    }
#pragma unroll
    for (int ks = 0; ks < 4; ++ks) {
        int koff = ks * 32 + quad * 8;
        bf16x8 b0  = *(const bf16x8*)(&sM[c][koff]);
        bf16x8 b1v = *(const bf16x8*)(&sM[16 + c][koff]);
#pragma unroll
        for (int ct = 0; ct < 2; ++ct) {
            bf16x8 a = *(const bf16x8*)(Wub + (size_t)(mbase + ct * 16 + c) * 256 + 128 + koff);
            acc[0][ct] = mfma_bf16(a, b0, acc[0][ct]);
            acc[1][ct] = mfma_bf16(a, b1v, acc[1][ct]);
        }
    }

    if (DOLIN1) __syncthreads();   // all update-GEMM sT reads done before overwrite

    // epilogue: hn = acc + bu + h -> global (and, if DOLIN1, bf16 -> sT)
#pragma unroll
    for (int st = 0; st < 2; ++st) {
        int node = n0 + st * 16 + c;
        if (node < N_NODES) {
#pragma unroll
            for (int ct = 0; ct < 2; ++ct) {
                int col = mbase + ct * 16 + quad * 4;
                float4 bv = *(const float4*)(bu + col);
                float4 rv = *(const float4*)(h + (size_t)node * 128 + col);
                float4 o;
                o.x = acc[st][ct][0] + bv.x + rv.x;
                o.y = acc[st][ct][1] + bv.y + rv.y;
                o.z = acc[st][ct][2] + bv.z + rv.z;
                o.w = acc[st][ct][3] + bv.w + rv.w;
                *(float4*)(h_out + (size_t)node * 128 + col) = o;
                if (DOLIN1) {
                    uint2 p; p.x = pack2(o.x, o.y); p.y = pack2(o.z, o.w);
                    *(uint2*)(&sT[st * 16 + c][col]) = p;
                }
            }
        }
    }

    // ---- phase 3: xf = hn @ lin1[l+1]^T (grid is exact: 625*32 = 20000)
    if (DOLIN1) {
        __syncthreads();
#pragma unroll
        for (int st = 0; st < 2; ++st)
#pragma unroll
            for (int ct = 0; ct < 2; ++ct) acc[st][ct] = (f32x4){0.f, 0.f, 0.f, 0.f};
#pragma unroll
        for (int ks = 0; ks < 4; ++ks) {
            int koff = ks * 32 + quad * 8;
            bf16x8 b0  = *(const bf16x8*)(&sT[c][koff]);
            bf16x8 b1v = *(const bf16x8*)(&sT[16 + c][koff]);
#pragma unroll
            for (int ct = 0; ct < 2; ++ct) {
                bf16x8 a = *(const bf16x8*)(lin1n + (size_t)(mbase + ct * 16 + c) * 128 + koff);
                acc[0][ct] = mfma_bf16(a, b0, acc[0][ct]);
                acc[1][ct] = mfma_bf16(a, b1v, acc[1][ct]);
            }
        }
#pragma unroll
        for (int st = 0; st < 2; ++st) {
            int node = n0 + st * 16 + c;
            if (node < N_NODES) {
#pragma unroll
                for (int ct = 0; ct < 2; ++ct) {
                    int col = mbase + ct * 16 + quad * 4;
                    uint2 p;
                    p.x = pack2(acc[st][ct][0], acc[st][ct][1]);
                    p.y = pack2(acc[st][ct][2], acc[st][ct][3]);
                    *(uint2*)(xf_out + (size_t)node * 128 + col) = p;
                }
            }
        }
    }
}

// ---------------------------------------------------------------------------
// Segment sum, vectorized: half-wave per edge (8B uint2 loads, 32 lanes x 8B
// = one coalesced 256B row), two edges in flight per iter, shfl-combine.
// Old version: full wave per edge with 4B loads -> deg-long chain of narrow
// dependent gathers.
__global__ __launch_bounds__(256) void segsum_kernel(
    const ushort_t* __restrict__ wf, const ushort_t* __restrict__ xf_bf,
    const int* __restrict__ row_start, const int* __restrict__ src_p,
    float* __restrict__ m_i) {
    int t = threadIdx.x, lane = t & 63;
    int n = blockIdx.x * 4 + (t >> 6);
    int half = lane >> 5;          // 0 or 1: which edge of the pair
    int cg = (lane & 31) * 4;      // 4-col group
    int beg = row_start[n], end = row_start[n + 1];
    float a0 = 0.f, a1 = 0.f, a2 = 0.f, a3 = 0.f;
    for (int i = beg + half; i < end; i += 2) {
        uint2 w = *(const uint2*)(wf + (size_t)i * 128 + cg);
        uint2 x = *(const uint2*)(xf_bf + (size_t)src_p[i] * 128 + cg);
        a0 += bf16lo(w.x) * bf16lo(x.x);
        a1 += bf16hi(w.x) * bf16hi(x.x);
        a2 += bf16lo(w.y) * bf16lo(x.y);
        a3 += bf16hi(w.y) * bf16hi(x.y);
    }
    a0 += __shfl_xor(a0, 32);
    a1 += __shfl_xor(a1, 32);
    a2 += __shfl_xor(a2, 32);
    a3 += __shfl_xor(a3, 32);
    if (half == 0)
        *(float4*)(m_i + (size_t)n * 128 + cg) = make_float4(a0, a1, a2, a3);
}

// ---------------------------------------------------------------------------
extern "C" void kernel_launch(void* const* d_in, const int* in_sizes, int n_in,
                              void* d_out, int out_size, void* d_ws, size_t ws_size,
                              hipStream_t stream) {
    const float* z        = (const float*)d_in[0];
    const int*   ei       = (const int*)d_in[1];
    const float* el       = (const float*)d_in[2];
    const float* ea       = (const float*)d_in[3];
    const float* emblin_w = (const float*)d_in[4];
    const float* emblin_b = (const float*)d_in[5];
    const float* mlp_w1   = (const float*)d_in[6];
    const float* mlp_b1   = (const float*)d_in[7];
    const float* mlp_w2   = (const float*)d_in[8];
    const float* mlp_b2   = (const float*)d_in[9];
    const float* lin1_w   = (const float*)d_in[10];
    const float* lin2_w   = (const float*)d_in[11];
    const float* lin2_b   = (const float*)d_in[12];
    const float* lin_w    = (const float*)d_in[13];
    const float* lin_b    = (const float*)d_in[14];
    (void)in_sizes; (void)n_in; (void)out_size; (void)ws_size;

    const size_t ND = (size_t)N_NODES * D;
    float* ws   = (float*)d_ws;
    float* h    = ws;                // N*D fp32
    float* m_i  = h + ND;            // N*D fp32
    float* cm_p = m_i + ND;          // E fp32 (cutoff mask, CSR-permuted)
    float* fend = cm_p + E_EDGES;

    ushort_t* w1b    = (ushort_t*)fend;                     // L*D*128
    ushort_t* w2b    = w1b   + (size_t)L_LAYERS * D * 128;  // L*D*D
    ushort_t* lin1b  = w2b   + (size_t)L_LAYERS * D * D;    // L*D*D
    ushort_t* lin2b  = lin1b + (size_t)L_LAYERS * D * D;    // L*D*D
    ushort_t* linwb  = lin2b + (size_t)L_LAYERS * D * D;    // L*D*256
    ushort_t* wf     = linwb + (size_t)L_LAYERS * D * 256;  // E*128
    ushort_t* xf_bf  = wf    + (size_t)E_EDGES * 128;       // N*128
    ushort_t* attr_p = xf_bf + ND;                          // E*128 (bf16, permuted, k-padded)
    int* ibase      = (int*)(attr_p + (size_t)E_EDGES * 128);
    int* deg        = ibase;                 // N
    int* row_start  = deg + N_NODES;         // N+1
    int* cursor     = row_start + N_NODES + 1;
    int* perm       = cursor + N_NODES;      // E
    int* src_p      = perm + E_EDGES;        // E

    // one-time weight prep (all bf16, row-major [out][k] = A-fragment layout)
    convw1_kernel<<<(L_LAYERS * D * 128) / 256, 256, 0, stream>>>(mlp_w1, w1b);
    castbf_kernel<<<(L_LAYERS * D * D) / 256, 256, 0, stream>>>(mlp_w2, w2b);
    castbf_kernel<<<(L_LAYERS * D * D) / 256, 256, 0, stream>>>(lin1_w, lin1b);
    castbf_kernel<<<(L_LAYERS * D * D) / 256, 256, 0, stream>>>(lin2_w, lin2b);
    castbf_kernel<<<(L_LAYERS * D * 256) / 256, 256, 0, stream>>>(lin_w, linwb);

    // CSR build
    hipMemsetAsync(deg, 0, (size_t)N_NODES * sizeof(int), stream);
    hist_kernel<<<E_EDGES / 256, 256, 0, stream>>>(ei, deg);
    scan_kernel<<<1, 1024, 0, stream>>>(deg, row_start, cursor);
    scatter_perm_kernel<<<E_EDGES / 256, 256, 0, stream>>>(ei, el, cursor, perm, src_p, cm_p);
    // one-time attr gather->bf16->permuted (hoisted out of the layer loop)
    attr_perm_kernel<<<(E_EDGES * 32) / 256, 256, 0, stream>>>(ea, perm, attr_p);

    embed_kernel<<<N_NODES, D, 0, stream>>>(z, emblin_w, emblin_b, h);

    const int NBLK = (N_NODES + 31) / 32;   // 625 (exact: 625*32 = 20000)
    // layer-0 lin1 from embed's h; subsequent xf comes from fused_tail phase 3
    lin1_kernel<<<NBLK, 256, 0, stream>>>(h, lin1b, xf_bf);
    for (int l = 0; l < L_LAYERS; ++l) {
        edge_mlp_kernel<<<E_EDGES / 32, 128, 0, stream>>>(
            attr_p, cm_p, w1b + (size_t)l * D * 128, mlp_b1 + (size_t)l * D,
            w2b + (size_t)l * D * D, mlp_b2 + (size_t)l * D, wf);
        segsum_kernel<<<N_NODES / 4, 256, 0, stream>>>(wf, xf_bf, row_start, src_p, m_i);
        // fused: m = ssp(m_i@lin2^T+b); h += concat(h,m)@lin_w^T+b; xf(l+1)
        if (l + 1 < L_LAYERS) {
            fused_tail_kernel<true><<<NBLK, 256, 0, stream>>>(
                m_i, h, lin2b + (size_t)l * D * D, lin2_b + (size_t)l * D,
                linwb + (size_t)l * D * 256, lin_b + (size_t)l * D,
                lin1b + (size_t)(l + 1) * D * D, h, xf_bf);
        } else {
            fused_tail_kernel<false><<<NBLK, 256, 0, stream>>>(
                m_i, h, lin2b + (size_t)l * D * D, lin2_b + (size_t)l * D,
                linwb + (size_t)l * D * 256, lin_b + (size_t)l * D,
                nullptr, h, nullptr);
        }
    }

    hipMemcpyAsync(d_out, h, ND * sizeof(float), hipMemcpyDeviceToDevice, stream);
}